// Round 1
// baseline (2033.490 us; speedup 1.0000x reference)
//
#include <hip/hip_runtime.h>
#include <stdint.h>

#define T_STEPS 200
#define BATCH   256
#define OBSD    128
#define HID     128
#define LATD    32
#define NSAMP   50
#define BS_TOT  12800      // BATCH*NSAMP
#define KIN     160        // OBS + L

#define OUT_ENT_OFF 81920000   // S*B*T*L
#define OUT_LP_OFF  84480000   // + S*B*T

typedef short  bf16x8 __attribute__((ext_vector_type(8)));
typedef float  f32x4  __attribute__((ext_vector_type(4)));
typedef uint32_t u32;

__device__ __forceinline__ uint16_t f2bf(float f) {
    u32 u = __builtin_bit_cast(u32, f);
    u32 r = (u + 0x7fffu + ((u >> 16) & 1u)) >> 16;
    return (uint16_t)r;
}
__device__ __forceinline__ float bf2f(u32 bits16) {
    u32 u = bits16 << 16;
    return __builtin_bit_cast(float, u);
}
__device__ __forceinline__ u32 pack2(float a, float b) {
    return (u32)f2bf(a) | ((u32)f2bf(b) << 16);
}

// ---------------------------------------------------------------------------
// Kernel 1: precompute xg[t][b][gate] = x_t @ W_ih_x^T + b_ih + b_hh  (bf16)
// stored in the MAIN kernel's per-(wave,lane) fragment order so the main
// kernel reads 8x dwordx4 per lane per step.
// Block = (t, bquad): grid 800. Same 512-thread wave/lane mapping as main.
// ---------------------------------------------------------------------------
__global__ __launch_bounds__(512, 2) void xg_prep(
    const float* __restrict__ x,      // [B][T][OBS]
    const float* __restrict__ W_ih,   // [512][160]
    const float* __restrict__ b_ih,   // [512]
    const float* __restrict__ b_hh,   // [512]
    uint16_t* __restrict__ xg)
{
    const int blk = blockIdx.x;            // t*4 + bq
    const int t   = blk >> 2, bq = blk & 3;
    const int tid = threadIdx.x;
    const int w = tid >> 6, l = tid & 63, lg = l >> 4, ln = l & 15;
    const int b0 = bq * 64;

    // B-operand fragments: B[k][col] = W_ih[col][k], k<128 (x part)
    bf16x8 wb[4][4];
    float  bias[4];
    #pragma unroll
    for (int q = 0; q < 4; ++q) {
        const int col = q * 128 + w * 16 + ln;
        bias[q] = b_ih[col] + b_hh[col];
        #pragma unroll
        for (int ks = 0; ks < 4; ++ks) {
            bf16x8 v;
            #pragma unroll
            for (int e = 0; e < 8; ++e)
                v[e] = (short)f2bf(W_ih[col * KIN + ks * 32 + lg * 8 + e]);
            wb[ks][q] = v;
        }
    }

    f32x4 acc[4][4];
    const f32x4 vz = {0.f, 0.f, 0.f, 0.f};
    #pragma unroll
    for (int rt = 0; rt < 4; ++rt)
        #pragma unroll
        for (int q = 0; q < 4; ++q) acc[rt][q] = vz;

    #pragma unroll
    for (int ks = 0; ks < 4; ++ks) {
        bf16x8 a[4];
        #pragma unroll
        for (int rt = 0; rt < 4; ++rt) {
            const int brow = b0 + rt * 16 + ln;   // A row m -> batch index
            const float* src = x + ((size_t)brow * T_STEPS + t) * OBSD + ks * 32 + lg * 8;
            bf16x8 v;
            #pragma unroll
            for (int e = 0; e < 8; ++e) v[e] = (short)f2bf(src[e]);
            a[rt] = v;
        }
        #pragma unroll
        for (int rt = 0; rt < 4; ++rt)
            #pragma unroll
            for (int q = 0; q < 4; ++q)
                acc[rt][q] = __builtin_amdgcn_mfma_f32_16x16x32_bf16(
                    a[rt], wb[ks][q], acc[rt][q], 0, 0, 0);
    }

    // pack in fragment order j=(rt*4+q)*4+e, two uint4 per rt
    uint4* dst = (uint4*)xg + ((size_t)blk * 512 + tid) * 8;
    #pragma unroll
    for (int rt = 0; rt < 4; ++rt) {
        float v0[4], v1[4], v2[4], v3[4];
        #pragma unroll
        for (int e = 0; e < 4; ++e) {
            v0[e] = acc[rt][0][e] + bias[0];
            v1[e] = acc[rt][1][e] + bias[1];
            v2[e] = acc[rt][2][e] + bias[2];
            v3[e] = acc[rt][3][e] + bias[3];
        }
        uint4 o0, o1;
        o0.x = pack2(v0[0], v0[1]); o0.y = pack2(v0[2], v0[3]);
        o0.z = pack2(v1[0], v1[1]); o0.w = pack2(v1[2], v1[3]);
        o1.x = pack2(v2[0], v2[1]); o1.y = pack2(v2[2], v2[3]);
        o1.z = pack2(v3[0], v3[1]); o1.w = pack2(v3[2], v3[3]);
        dst[2 * rt]     = o0;
        dst[2 * rt + 1] = o1;
    }
}

// ---------------------------------------------------------------------------
// Kernel 2: entropies = const everywhere
// ---------------------------------------------------------------------------
__global__ void ent_fill(const float* __restrict__ cov, float* __restrict__ out)
{
    __shared__ float ec;
    if (threadIdx.x == 0) {
        float logdet = 0.f;
        for (int i = 0; i < LATD; ++i) logdet += logf(cov[i]);
        ec = 0.5f * 32.f * (1.f + 1.8378770664093453f) + 0.5f * logdet;
    }
    __syncthreads();
    const int idx = blockIdx.x * blockDim.x + threadIdx.x;
    const int stride = gridDim.x * blockDim.x;
    for (int i = idx; i < 2560000; i += stride)
        out[OUT_ENT_OFF + i] = ec;
}

// ---------------------------------------------------------------------------
// Kernel 3: the recurrence. 200 blocks x 512 threads (8 waves).
// Block owns 64 rows (bs0..bs0+63), loops t=0..199.
// Wave w owns gate columns {q*128 + w*16 + ln} (col-tiles w, w+8, w+16, w+24)
// -> LSTM elementwise is wave-local, c-state lives in registers.
// zh LDS tile: [64 rows][168] bf16 (cols 0-31 = z, 32-159 = h, pad 8).
// ---------------------------------------------------------------------------
__global__ __launch_bounds__(512, 2) void lstm_main(
    const float* __restrict__ eps,    // [T][BS][L]
    const float* __restrict__ W_ih,   // [512][160]
    const float* __restrict__ W_hh,   // [512][128]
    const float* __restrict__ W_mu,   // [32][128]
    const float* __restrict__ b_mu,   // [32]
    const float* __restrict__ cov,    // [32]
    const uint16_t* __restrict__ xg,
    float* __restrict__ out)
{
    __shared__ uint16_t zh[64 * 168];
    __shared__ float lpbuf[2 * 64];

    const int blk = blockIdx.x;
    const int bq  = blk & 3;
    const int bs0 = blk * 64;
    const int tid = threadIdx.x;
    const int w = tid >> 6, l = tid & 63, lg = l >> 4, ln = l & 15;

    // resident recurrent weight fragments
    bf16x8 wz[4];      // k-step 0: z part, B[k][col] = W_ih[col][128+k]
    bf16x8 wh[4][4];   // k-steps 1..4: h part, W_hh[col][k]
    #pragma unroll
    for (int q = 0; q < 4; ++q) {
        const int col = q * 128 + w * 16 + ln;
        {
            bf16x8 v;
            #pragma unroll
            for (int e = 0; e < 8; ++e)
                v[e] = (short)f2bf(W_ih[col * KIN + 128 + lg * 8 + e]);
            wz[q] = v;
        }
        #pragma unroll
        for (int ks = 0; ks < 4; ++ks) {
            bf16x8 v;
            #pragma unroll
            for (int e = 0; e < 8; ++e)
                v[e] = (short)f2bf(W_hh[col * HID + ks * 32 + lg * 8 + e]);
            wh[ks][q] = v;
        }
    }

    // mean-phase: wave w computes output tile (rtm = w>>1, ctm = w&1)
    const int rtm = w >> 1, ctm = w & 1;
    const int zcol = ctm * 16 + ln;
    bf16x8 wmu[4];
    #pragma unroll
    for (int ks = 0; ks < 4; ++ks) {
        bf16x8 v;
        #pragma unroll
        for (int e = 0; e < 8; ++e)
            v[e] = (short)f2bf(W_mu[zcol * HID + ks * 32 + lg * 8 + e]);
        wmu[ks] = v;
    }
    const float stdv = sqrtf(cov[zcol]);
    const float bmu  = b_mu[zcol];
    float logdet = 0.f;
    for (int i = 0; i < LATD; ++i) logdet += logf(cov[i]);
    const float lconst = 32.f * 1.8378770664093453f + logdet;

    for (int i = tid; i < 64 * 168; i += 512) zh[i] = 0;
    f32x4 cstate[4];
    const f32x4 vz4 = {0.f, 0.f, 0.f, 0.f};
    #pragma unroll
    for (int rt = 0; rt < 4; ++rt) cstate[rt] = vz4;
    __syncthreads();

    for (int t = 0; t < T_STEPS; ++t) {
        // ---- gates MFMA: [64 x 512] += zh[64 x 160] * Wrec[160 x 512] ----
        f32x4 acc[4][4];
        #pragma unroll
        for (int rt = 0; rt < 4; ++rt)
            #pragma unroll
            for (int q = 0; q < 4; ++q) acc[rt][q] = vz4;
        #pragma unroll
        for (int ks = 0; ks < 5; ++ks) {
            bf16x8 a[4];
            #pragma unroll
            for (int rt = 0; rt < 4; ++rt)
                a[rt] = *(const bf16x8*)&zh[(rt * 16 + ln) * 168 + ks * 32 + lg * 8];
            #pragma unroll
            for (int rt = 0; rt < 4; ++rt)
                #pragma unroll
                for (int q = 0; q < 4; ++q)
                    acc[rt][q] = __builtin_amdgcn_mfma_f32_16x16x32_bf16(
                        a[rt], (ks == 0) ? wz[q] : wh[ks - 1][q], acc[rt][q], 0, 0, 0);
        }

        // issue xg + eps loads early (consumed after the barrier)
        const uint4* xp = (const uint4*)xg + ((size_t)(t * 4 + bq) * 512 + tid) * 8;
        uint4 xv[8];
        #pragma unroll
        for (int i = 0; i < 8; ++i) xv[i] = xp[i];
        float ev[4];
        {
            const float* ep = eps + ((size_t)t * BS_TOT + bs0 + rtm * 16 + lg * 4) * LATD + zcol;
            #pragma unroll
            for (int e = 0; e < 4; ++e) ev[e] = ep[e * LATD];
        }

        __syncthreads();   // barrier 1: all zh reads of this step done

        // ---- LSTM elementwise (wave-local h columns w*16+ln) ----
        #pragma unroll
        for (int rt = 0; rt < 4; ++rt) {
            const uint4 u01 = xv[2 * rt], u23 = xv[2 * rt + 1];
            const float xi[4] = { bf2f(u01.x & 0xffff), bf2f(u01.x >> 16),
                                  bf2f(u01.y & 0xffff), bf2f(u01.y >> 16) };
            const float xf[4] = { bf2f(u01.z & 0xffff), bf2f(u01.z >> 16),
                                  bf2f(u01.w & 0xffff), bf2f(u01.w >> 16) };
            const float xgv[4] = { bf2f(u23.x & 0xffff), bf2f(u23.x >> 16),
                                   bf2f(u23.y & 0xffff), bf2f(u23.y >> 16) };
            const float xo[4] = { bf2f(u23.z & 0xffff), bf2f(u23.z >> 16),
                                  bf2f(u23.w & 0xffff), bf2f(u23.w >> 16) };
            #pragma unroll
            for (int e = 0; e < 4; ++e) {
                const float iv = acc[rt][0][e] + xi[e];
                const float fv = acc[rt][1][e] + xf[e];
                const float gv = acc[rt][2][e] + xgv[e];
                const float ov = acc[rt][3][e] + xo[e];
                const float si = 1.f / (1.f + __expf(-iv));
                const float sf = 1.f / (1.f + __expf(-fv));
                const float so = 1.f / (1.f + __expf(-ov));
                const float tg = tanhf(gv);
                const float c  = sf * cstate[rt][e] + si * tg;
                cstate[rt][e] = c;
                const float h = so * tanhf(c);
                const int row = rt * 16 + lg * 4 + e;   // D-layout row
                zh[row * 168 + 32 + w * 16 + ln] = f2bf(h);
            }
        }

        __syncthreads();   // barrier 2: h ready in LDS

        // ---- mean MFMA: one 16x16 tile per wave, K=128 over h ----
        f32x4 macc = vz4;
        #pragma unroll
        for (int ks = 0; ks < 4; ++ks) {
            const bf16x8 a = *(const bf16x8*)&zh[(rtm * 16 + ln) * 168 + 32 + ks * 32 + lg * 8];
            macc = __builtin_amdgcn_mfma_f32_16x16x32_bf16(a, wmu[ks], macc, 0, 0, 0);
        }

        float ps[4];
        #pragma unroll
        for (int e = 0; e < 4; ++e) {
            const int row = rtm * 16 + lg * 4 + e;
            const float z = macc[e] + bmu + ev[e] * stdv;
            out[(size_t)(bs0 + row) * 6400 + t * 32 + zcol] = z;
            zh[row * 168 + zcol] = f2bf(z);
            ps[e] = ev[e] * ev[e];
        }
        // reduce eps^2 over the 16 ln-lanes (cols of this tile)
        #pragma unroll
        for (int m = 1; m < 16; m <<= 1) {
            #pragma unroll
            for (int e = 0; e < 4; ++e) ps[e] += __shfl_xor(ps[e], m, 64);
        }
        if (ln == 0) {
            #pragma unroll
            for (int e = 0; e < 4; ++e)
                lpbuf[ctm * 64 + rtm * 16 + lg * 4 + e] = ps[e];
        }

        __syncthreads();   // barrier 3: z + lpbuf ready (next step may start)

        if (ctm == 0 && ln == 0) {
            #pragma unroll
            for (int e = 0; e < 4; ++e) {
                const int row = rtm * 16 + lg * 4 + e;
                const float tot = ps[e] + lpbuf[64 + row];
                out[OUT_LP_OFF + (size_t)(bs0 + row) * 200 + t] = -0.5f * (tot + lconst);
            }
        }
    }
}

extern "C" void kernel_launch(void* const* d_in, const int* in_sizes, int n_in,
                              void* d_out, int out_size, void* d_ws, size_t ws_size,
                              hipStream_t stream) {
    const float* x    = (const float*)d_in[0];
    const float* eps  = (const float*)d_in[1];
    const float* W_ih = (const float*)d_in[2];
    const float* W_hh = (const float*)d_in[3];
    const float* b_ih = (const float*)d_in[4];
    const float* b_hh = (const float*)d_in[5];
    const float* W_mu = (const float*)d_in[6];
    const float* b_mu = (const float*)d_in[7];
    const float* cov  = (const float*)d_in[8];
    float* out = (float*)d_out;
    uint16_t* xg = (uint16_t*)d_ws;   // needs 52,428,800 bytes

    hipLaunchKernelGGL(xg_prep, dim3(800), dim3(512), 0, stream, x, W_ih, b_ih, b_hh, xg);
    hipLaunchKernelGGL(ent_fill, dim3(2048), dim3(256), 0, stream, cov, out);
    hipLaunchKernelGGL(lstm_main, dim3(200), dim3(512), 0, stream,
                       eps, W_ih, W_hh, W_mu, b_mu, cov, xg, out);
}